// Round 9
// baseline (152.614 us; speedup 1.0000x reference)
//
#include <hip/hip_runtime.h>
#include <hip/hip_bf16.h>
#include <stdint.h>

// FlatCritic: B=128, L=512, D_DESC=768, D_STD=128, D_ACT=128, D_CTX=1152, H=512
// out = [q (B*L f32), emb (B*L*128 f32)]
//
// v9 = v8 (mlp/prologue byte-identical) + emb 2-chunk-deep pipeline:
//   two reg staging sets + 3 LDS buffers + loads issued 2 chunks ahead,
//   chunk loop fully unrolled (static stg indices).

typedef __attribute__((ext_vector_type(8))) short short8_t;
typedef __attribute__((ext_vector_type(4))) short short4_t;
typedef __attribute__((ext_vector_type(4))) float f32x4;
typedef __attribute__((ext_vector_type(4))) unsigned int u32x4;

__device__ inline unsigned short f2bf(float f) {
  union { float f; unsigned u; } v; v.f = f;
  unsigned r = v.u + 0x7FFFu + ((v.u >> 16) & 1u);
  return (unsigned short)(r >> 16);
}

// A-frag pack (mb-major): dst[((mb*NKS+ks)*64+l)*8+j] = bf16(src[(k0+ks*32+(l>>4)*8+j)*ldc + mb*16+(l&15)])
__device__ inline void pack_frags(const float* __restrict__ src, int ldc, int k0, int NKS,
                                  unsigned short* __restrict__ dst, int total, int tid, int n) {
  for (int fi = tid; fi < total; fi += n) {
    int j = fi & 7, lane = (fi >> 3) & 63, rest = fi >> 9;
    int ks = rest % NKS, mb = rest / NKS;
    int c = mb * 16 + (lane & 15);
    int k = k0 + ks * 32 + ((lane >> 4) << 3) + j;
    dst[fi] = f2bf(src[(size_t)k * ldc + c]);
  }
}

__global__ __launch_bounds__(256) void prep_pack(
    const float* __restrict__ Wd, const float* __restrict__ Ws,
    const float* __restrict__ W1, const float* __restrict__ W2,
    unsigned short* __restrict__ wdf, unsigned short* __restrict__ wsf,
    unsigned short* __restrict__ w1f, unsigned short* __restrict__ w2f) {
  int tid = blockIdx.x * 256 + threadIdx.x, n = gridDim.x * 256;
  pack_frags(Wd, 128, 0,    24, wdf,  98304,  tid, n);   // desc proj  [8mb][24ks]
  pack_frags(Ws, 128, 0,    4,  wsf,  16384,  tid, n);   // std proj   [8mb][4ks]
  pack_frags(W1, 512, 1152, 4,  w1f,  65536,  tid, n);   // W1[1152:]  [32mb][4ks]
  pack_frags(W2, 512, 0,    16, w2f,  262144, tid, n);   // W2         [32mb][16ks]
}

// ---------------- cc[b][h] = b1[h] + ctx(b).W1[:1152,h]  (fp32 exact) ----------------
__global__ __launch_bounds__(256) void ctx_cc(
    const float* __restrict__ instr, const float* __restrict__ state, const float* __restrict__ hidden,
    const float* __restrict__ W1, const float* __restrict__ b1, float* __restrict__ cc) {
  int bid = blockIdx.x;
  int b = bid >> 2, part = bid & 3;
  __shared__ float ctx[1152];
  __shared__ float red[256];
  int t = threadIdx.x;
  for (int i = t; i < 512; i += 256) { ctx[i] = instr[b * 512 + i]; ctx[512 + i] = state[b * 512 + i]; }
  if (t < 128) ctx[1024 + t] = hidden[b * 128 + t];
  __syncthreads();
  int hcol = part * 128 + (t & 127);
  int half = t >> 7;
  float acc = 0.f;
  const float* wp = W1 + (size_t)half * 576 * 512 + hcol;
  #pragma unroll 8
  for (int d = 0; d < 576; ++d) acc = fmaf(ctx[half * 576 + d], wp[(size_t)d * 512], acc);
  red[t] = acc;
  __syncthreads();
  if (t < 128) cc[b * 512 + hcol] = red[t] + red[t + 128] + b1[hcol];
}

// ---------------- q_inv[b]: MLP tail on emb=0 rows (f32 W2) ----------------
__global__ __launch_bounds__(256) void qinv_kernel(
    const float* __restrict__ cc, const float* __restrict__ W2, const float* __restrict__ b2,
    const float* __restrict__ W3, const float* __restrict__ b3, float* __restrict__ qinv) {
  int b = blockIdx.x, t = threadIdx.x;
  __shared__ float h1s[512];
  __shared__ float red[256];
  for (int i = t; i < 512; i += 256) h1s[i] = fmaxf(cc[b * 512 + i], 0.f);
  __syncthreads();
  float a0 = b2[t], a1 = b2[t + 256];
  #pragma unroll 4
  for (int c = 0; c < 512; ++c) {
    float x = h1s[c];
    a0 = fmaf(x, W2[(size_t)c * 512 + t], a0);
    a1 = fmaf(x, W2[(size_t)c * 512 + t + 256], a1);
  }
  red[t] = fmaxf(a0, 0.f) * W3[t] + fmaxf(a1, 0.f) * W3[t + 256];
  __syncthreads();
  for (int s = 128; s > 0; s >>= 1) { if (t < s) red[t] += red[t + s]; __syncthreads(); }
  if (t == 0) qinv[b] = fmaxf(red[0] + b3[0], 0.f);
}

// ---------------- E: emb producer. 32-row tiles, 256 threads, grid (16,128) ----------------
// v9: 2-chunk-deep load pipeline, 3 LDS buffers, fully unrolled chunk loop.
// embB[(((tile*4+ks)*2+nb)*64 + lane)*8 + j] = bf16emb[r=nb*16+(lane&15)][k=ks*32+(lane>>4)*8+j]
__global__ __launch_bounds__(256, 4) void emb_kernel(
    const float* __restrict__ adesc, const float* __restrict__ astd,
    const int* __restrict__ type_ids, const int* __restrict__ lengths,
    const float* __restrict__ bdesc, const float* __restrict__ bstd,
    const unsigned short* __restrict__ wdf, const unsigned short* __restrict__ wsf,
    float* __restrict__ embout, unsigned short* __restrict__ embB) {
  int b = blockIdx.y, lt = blockIdx.x;
  int l0 = lt * 32;
  int t = threadIdx.x;
  int tile = b * 16 + lt;
  int len = lengths[b];
  int nv = len - l0; nv = nv < 0 ? 0 : (nv > 32 ? 32 : nv);
  f32x4 zero4 = {0.f, 0.f, 0.f, 0.f};

  if (nv == 0) {  // fully-invalid tile: emb = 0, embB = 0 (q handled by M)
    float* ep = embout + (size_t)(b * 512 + l0) * 128;
    #pragma unroll
    for (int i = 0; i < 4; ++i) ((f32x4*)ep)[t + i * 256] = zero4;
    u32x4 z4 = {0u, 0u, 0u, 0u};
    u32x4* bp = (u32x4*)(embB + (size_t)tile * 4096);
    bp[t] = z4; bp[t + 256] = z4;
    return;
  }

  __shared__ __align__(16) unsigned short act[3][32 * 136];  // 26.1 KB, 3-deep ring
  __shared__ int typeL[32];
  int w = t >> 6, l = t & 63, g = l >> 4, ln = l & 15;

  if (t < 32) typeL[t] = type_ids[b * 512 + l0 + t];

  const float* descB = adesc + (size_t)(b * 512 + l0) * 768;
  const float* stdB  = astd  + (size_t)(b * 512 + l0) * 128;

  __syncthreads();  // typeL ready

  int r0 = t >> 5, c4 = t & 31;

  f32x4 stgA[4], stgB[4];

  // issue chunk kc's loads into the named staging set (static choice)
  auto issueA = [&](int kc) {
    bool isStd = (kc == 6);
    #pragma unroll
    for (int i = 0; i < 4; ++i) {
      int r = r0 + i * 8;
      bool ok = (r < nv) && ((typeL[r] == 0) != isStd);
      f32x4 v = zero4;
      if (ok) v = isStd ? *(const f32x4*)(stdB + (size_t)r * 128 + c4 * 4)
                        : *(const f32x4*)(descB + (size_t)r * 768 + kc * 128 + c4 * 4);
      stgA[i] = v;
    }
  };
  auto issueB = [&](int kc) {
    bool isStd = (kc == 6);
    #pragma unroll
    for (int i = 0; i < 4; ++i) {
      int r = r0 + i * 8;
      bool ok = (r < nv) && ((typeL[r] == 0) != isStd);
      f32x4 v = zero4;
      if (ok) v = isStd ? *(const f32x4*)(stdB + (size_t)r * 128 + c4 * 4)
                        : *(const f32x4*)(descB + (size_t)r * 768 + kc * 128 + c4 * 4);
      stgB[i] = v;
    }
  };
  auto writeA = [&](int kc) {
    unsigned short* buf = act[kc % 3];
    #pragma unroll
    for (int i = 0; i < 4; ++i) {
      short4_t p;
      p[0] = (short)f2bf(stgA[i][0]); p[1] = (short)f2bf(stgA[i][1]);
      p[2] = (short)f2bf(stgA[i][2]); p[3] = (short)f2bf(stgA[i][3]);
      *(short4_t*)&buf[(r0 + i * 8) * 136 + c4 * 4] = p;
    }
  };
  auto writeB = [&](int kc) {
    unsigned short* buf = act[kc % 3];
    #pragma unroll
    for (int i = 0; i < 4; ++i) {
      short4_t p;
      p[0] = (short)f2bf(stgB[i][0]); p[1] = (short)f2bf(stgB[i][1]);
      p[2] = (short)f2bf(stgB[i][2]); p[3] = (short)f2bf(stgB[i][3]);
      *(short4_t*)&buf[(r0 + i * 8) * 136 + c4 * 4] = p;
    }
  };

  f32x4 acc[2][2];
  #pragma unroll
  for (int mb = 0; mb < 2; ++mb)
    #pragma unroll
    for (int nb = 0; nb < 2; ++nb) acc[mb][nb] = zero4;

  auto mfma_chunk = [&](int kc) {
    const unsigned short* buf = act[kc % 3];
    bool isStd = (kc == 6);
    #pragma unroll
    for (int ks = 0; ks < 4; ++ks) {
      short8_t bfr[2];
      #pragma unroll
      for (int nb = 0; nb < 2; ++nb)
        bfr[nb] = *(const short8_t*)&buf[(nb * 16 + ln) * 136 + ks * 32 + g * 8];
      #pragma unroll
      for (int mb = 0; mb < 2; ++mb) {
        const unsigned short* ap = isStd ? (wsf + ((((w * 2 + mb) * 4 + ks) * 64 + l) << 3))
                                         : (wdf + ((((w * 2 + mb) * 24 + kc * 4 + ks) * 64 + l) << 3));
        short8_t a = *(const short8_t*)ap;
        #pragma unroll
        for (int nb = 0; nb < 2; ++nb)
          acc[mb][nb] = __builtin_amdgcn_mfma_f32_16x16x32_bf16(a, bfr[nb], acc[mb][nb], 0, 0, 0);
      }
    }
  };

  // prologue: 2 chunks in flight
  issueA(0);
  issueB(1);

  // fully unrolled 7-chunk pipeline: write(k) [waits only k's loads], barrier,
  // issue(k+2) into just-freed staging set, MFMA(k).
  #pragma unroll
  for (int kc = 0; kc < 7; ++kc) {
    if ((kc & 1) == 0) writeA(kc); else writeB(kc);
    __syncthreads();
    if (kc + 2 <= 6) { if ((kc & 1) == 0) issueA(kc + 2); else issueB(kc + 2); }
    mfma_chunk(kc);
  }

  // epilogue: masked bias + f32 global store + bf16 -> E (act[1]; MFMA(6) read act[0])
  unsigned short* E = act[1];
  #pragma unroll
  for (int mb = 0; mb < 2; ++mb) {
    int k0 = w * 32 + mb * 16 + g * 4;
    f32x4 bd4 = *(const f32x4*)(bdesc + k0);
    f32x4 bs4 = *(const f32x4*)(bstd + k0);
    #pragma unroll
    for (int nb = 0; nb < 2; ++nb) {
      int r = nb * 16 + ln;
      f32x4 e = acc[mb][nb];
      if (r < nv) { f32x4 bias = (typeL[r] == 0) ? bd4 : bs4; e = e + bias; }
      else e = zero4;
      *(f32x4*)(embout + (size_t)(b * 512 + l0 + r) * 128 + k0) = e;
      short4_t p; p[0] = (short)f2bf(e[0]); p[1] = (short)f2bf(e[1]);
      p[2] = (short)f2bf(e[2]); p[3] = (short)f2bf(e[3]);
      *(short4_t*)&E[r * 136 + k0] = p;
    }
  }
  __syncthreads();

  // export B-frag-linear embB (coalesced 1KB stores)
  unsigned short* bbase = embB + (size_t)tile * 4096;
  #pragma unroll
  for (int ks = 0; ks < 4; ++ks)
    #pragma unroll
    for (int nb = 0; nb < 2; ++nb) {
      short8_t v = *(const short8_t*)&E[(nb * 16 + ln) * 136 + ks * 32 + g * 8];
      *(short8_t*)&bbase[((ks * 2 + nb) * 64 + l) * 8] = v;
    }
}

// ---------------- M: MLP. 128-row blocks, 512 thr, grid (4,128) ---- (v8, unchanged) ----
__global__ __launch_bounds__(512, 2) void mlp_kernel(
    const int* __restrict__ lengths,
    const float* __restrict__ b2, const float* __restrict__ W3, const float* __restrict__ b3,
    const unsigned short* __restrict__ w1f, const unsigned short* __restrict__ w2f,
    const float* __restrict__ cc, const float* __restrict__ qinv,
    const unsigned short* __restrict__ embB, float* __restrict__ qout) {
  int b = blockIdx.y, lt = blockIdx.x;
  int l0 = lt * 128;
  int t = threadIdx.x;
  int len = lengths[b];
  int nv = len - l0; nv = nv < 0 ? 0 : (nv > 128 ? 128 : nv);

  if (nv == 0) {
    if (t < 128) qout[(size_t)b * 512 + l0 + t] = qinv[b];
    return;
  }

  __shared__ __align__(16) unsigned short h1[128 * 512];  // XOR-swizzled
  __shared__ float qpart[8][128];
  int w = t >> 6, l = t & 63, g = l >> 4, ln = l & 15;

  // ===== S1
  f32x4 acc[4][8];
  #pragma unroll
  for (int mbi = 0; mbi < 4; ++mbi) {
    f32x4 ccv = *(const f32x4*)(cc + (size_t)b * 512 + (w * 4 + mbi) * 16 + g * 4);
    #pragma unroll
    for (int nb = 0; nb < 8; ++nb) acc[mbi][nb] = ccv;
  }
  const unsigned short* ebase = embB + (size_t)(b * 16 + lt * 4) * 4096;
  #pragma unroll
  for (int kk = 0; kk < 4; ++kk) {
    int ks = (kk + w) & 3;
    short8_t bfr[8];
    #pragma unroll
    for (int nb = 0; nb < 8; ++nb)
      bfr[nb] = *(const short8_t*)&ebase[(nb >> 1) * 4096 + ((ks * 2 + (nb & 1)) * 64 + l) * 8];
    short8_t a[4];
    #pragma unroll
    for (int mbi = 0; mbi < 4; ++mbi)
      a[mbi] = *(const short8_t*)(w1f + ((((w * 4 + mbi) * 4 + ks) * 64 + l) << 3));
    __builtin_amdgcn_s_setprio(1);
    #pragma unroll
    for (int mbi = 0; mbi < 4; ++mbi)
      #pragma unroll
      for (int nb = 0; nb < 8; ++nb)
        acc[mbi][nb] = __builtin_amdgcn_mfma_f32_16x16x32_bf16(a[mbi], bfr[nb], acc[mbi][nb], 0, 0, 0);
    __builtin_amdgcn_s_setprio(0);
  }
  #pragma unroll
  for (int mbi = 0; mbi < 4; ++mbi) {
    int c0 = (w * 4 + mbi) * 16 + g * 4;
    #pragma unroll
    for (int nb = 0; nb < 8; ++nb) {
      int r = nb * 16 + ln;
      f32x4 v = acc[mbi][nb];
      short4_t p;
      p[0] = (short)f2bf(fmaxf(v[0], 0.f)); p[1] = (short)f2bf(fmaxf(v[1], 0.f));
      p[2] = (short)f2bf(fmaxf(v[2], 0.f)); p[3] = (short)f2bf(fmaxf(v[3], 0.f));
      *(short4_t*)&h1[r * 512 + (c0 ^ ((r & 7) << 3))] = p;
    }
  }
  __syncthreads();

  // ===== S2
  #pragma unroll
  for (int mbi = 0; mbi < 4; ++mbi) {
    f32x4 b2v = *(const f32x4*)(b2 + (w * 4 + mbi) * 16 + g * 4);
    #pragma unroll
    for (int nb = 0; nb < 8; ++nb) acc[mbi][nb] = b2v;
  }
  int ks0 = (2 * w) & 15;
  short8_t aP[2][4];
  #pragma unroll
  for (int mbi = 0; mbi < 4; ++mbi)
    aP[0][mbi] = *(const short8_t*)(w2f + ((((w * 4 + mbi) * 16 + ks0) * 64 + l) << 3));
  #pragma unroll
  for (int kk = 0; kk < 16; ++kk) {
    int ksn = (kk + 1 + 2 * w) & 15;
    if (kk < 15) {
      #pragma unroll
      for (int mbi = 0; mbi < 4; ++mbi)
        aP[(kk + 1) & 1][mbi] =
            *(const short8_t*)(w2f + ((((w * 4 + mbi) * 16 + ksn) * 64 + l) << 3));
    }
    int ks = (kk + 2 * w) & 15;
    short8_t bfr[8];
    #pragma unroll
    for (int nb = 0; nb < 8; ++nb) {
      int row = nb * 16 + ln;
      bfr[nb] = *(const short8_t*)&h1[row * 512 + ((ks * 32 + g * 8) ^ ((row & 7) << 3))];
    }
    __builtin_amdgcn_s_setprio(1);
    #pragma unroll
    for (int mbi = 0; mbi < 4; ++mbi)
      #pragma unroll
      for (int nb = 0; nb < 8; ++nb)
        acc[mbi][nb] = __builtin_amdgcn_mfma_f32_16x16x32_bf16(aP[kk & 1][mbi], bfr[nb], acc[mbi][nb], 0, 0, 0);
    __builtin_amdgcn_s_setprio(0);
  }

  // ===== S3
  float part[8] = {0.f, 0.f, 0.f, 0.f, 0.f, 0.f, 0.f, 0.f};
  #pragma unroll
  for (int mbi = 0; mbi < 4; ++mbi) {
    int c0 = (w * 4 + mbi) * 16 + g * 4;
    f32x4 w3v = *(const f32x4*)(W3 + c0);
    #pragma unroll
    for (int nb = 0; nb < 8; ++nb) {
      f32x4 v = acc[mbi][nb];
      part[nb] += fmaxf(v[0], 0.f) * w3v[0] + fmaxf(v[1], 0.f) * w3v[1]
                + fmaxf(v[2], 0.f) * w3v[2] + fmaxf(v[3], 0.f) * w3v[3];
    }
  }
  #pragma unroll
  for (int nb = 0; nb < 8; ++nb) {
    float p = part[nb];
    p += __shfl_xor(p, 16, 64);
    p += __shfl_xor(p, 32, 64);
    if (g == 0) qpart[w][nb * 16 + ln] = p;
  }
  __syncthreads();
  if (t < 128) {
    float q = qpart[0][t] + qpart[1][t] + qpart[2][t] + qpart[3][t]
            + qpart[4][t] + qpart[5][t] + qpart[6][t] + qpart[7][t] + b3[0];
    qout[(size_t)b * 512 + l0 + t] = fmaxf(q, 0.f);
  }
}

extern "C" void kernel_launch(void* const* d_in, const int* in_sizes, int n_in,
                              void* d_out, int out_size, void* d_ws, size_t ws_size,
                              hipStream_t stream) {
  (void)in_sizes; (void)n_in; (void)out_size; (void)ws_size;
  const float* instr  = (const float*)d_in[0];
  const float* state  = (const float*)d_in[1];
  const float* hidden = (const float*)d_in[2];
  const float* adesc  = (const float*)d_in[3];
  const float* astd   = (const float*)d_in[4];
  const int*   tids   = (const int*)d_in[5];
  const int*   lens   = (const int*)d_in[6];
  const float* Wd = (const float*)d_in[7];
  const float* bd = (const float*)d_in[8];
  const float* Ws = (const float*)d_in[9];
  const float* bs = (const float*)d_in[10];
  const float* W1 = (const float*)d_in[11];
  const float* b1 = (const float*)d_in[12];
  const float* W2 = (const float*)d_in[13];
  const float* b2 = (const float*)d_in[14];
  const float* W3 = (const float*)d_in[15];
  const float* b3 = (const float*)d_in[16];

  float* qout = (float*)d_out;
  float* embout = qout + 128 * 512;

  char* ws = (char*)d_ws;
  unsigned short* wdf  = (unsigned short*)(ws);             // 196608 B
  unsigned short* wsf  = (unsigned short*)(ws + 196608);    //  32768 B
  unsigned short* w1f  = (unsigned short*)(ws + 229376);    // 131072 B
  unsigned short* w2f  = (unsigned short*)(ws + 360448);    // 524288 B
  float* cc   = (float*)(ws + 884736);                      // 262144 B
  float* qinv = (float*)(ws + 1146880);                     // 512 B
  unsigned short* embB = (unsigned short*)(ws + 1147392);   // 16777216 B

  prep_pack<<<256, 256, 0, stream>>>(Wd, Ws, W1, W2, wdf, wsf, w1f, w2f);
  ctx_cc<<<512, 256, 0, stream>>>(instr, state, hidden, W1, b1, cc);
  qinv_kernel<<<128, 256, 0, stream>>>(cc, W2, b2, W3, b3, qinv);
  emb_kernel<<<dim3(16, 128), 256, 0, stream>>>(adesc, astd, tids, lens, bd, bs,
                                                wdf, wsf, embout, embB);
  mlp_kernel<<<dim3(4, 128), 512, 0, stream>>>(lens, b2, W3, b3, w1f, w2f,
                                               cc, qinv, embB, qout);
}

// Round 10
// 146.289 us; speedup vs baseline: 1.0432x; 1.0432x over previous
//
#include <hip/hip_runtime.h>
#include <hip/hip_bf16.h>
#include <stdint.h>

// FlatCritic: B=128, L=512, D_DESC=768, D_STD=128, D_ACT=128, D_CTX=1152, H=512
// out = [q (B*L f32), emb (B*L*128 f32)]
//
// v10 = v8 (mlp/prologue byte-identical) + emb rebuilt on global_load_lds +
// counted vmcnt + raw s_barrier (T3/T4): 3-buffer f32 LDS ring, loads issued
// 2 chunks ahead, source-side XOR swizzle (rule #21), consume-side f32->bf16.

typedef __attribute__((ext_vector_type(8))) short short8_t;
typedef __attribute__((ext_vector_type(4))) short short4_t;
typedef __attribute__((ext_vector_type(4))) float f32x4;
typedef __attribute__((ext_vector_type(4))) unsigned int u32x4;

__device__ inline unsigned short f2bf(float f) {
  union { float f; unsigned u; } v; v.f = f;
  unsigned r = v.u + 0x7FFFu + ((v.u >> 16) & 1u);
  return (unsigned short)(r >> 16);
}

__device__ inline unsigned short cvt1(float f) {  // RNE, compiler fuses to cvt_pk
  __hip_bfloat16 h = __float2bfloat16(f);
  unsigned short u; __builtin_memcpy(&u, &h, 2);
  return u;
}

#define GLOAD_LDS16(gsrc, ldst)                                                  \
  __builtin_amdgcn_global_load_lds(                                              \
      (const __attribute__((address_space(1))) unsigned int*)(gsrc),             \
      (__attribute__((address_space(3))) unsigned int*)(ldst), 16, 0, 0)

// A-frag pack (mb-major): dst[((mb*NKS+ks)*64+l)*8+j] = bf16(src[(k0+ks*32+(l>>4)*8+j)*ldc + mb*16+(l&15)])
__device__ inline void pack_frags(const float* __restrict__ src, int ldc, int k0, int NKS,
                                  unsigned short* __restrict__ dst, int total, int tid, int n) {
  for (int fi = tid; fi < total; fi += n) {
    int j = fi & 7, lane = (fi >> 3) & 63, rest = fi >> 9;
    int ks = rest % NKS, mb = rest / NKS;
    int c = mb * 16 + (lane & 15);
    int k = k0 + ks * 32 + ((lane >> 4) << 3) + j;
    dst[fi] = f2bf(src[(size_t)k * ldc + c]);
  }
}

__global__ __launch_bounds__(256) void prep_pack(
    const float* __restrict__ Wd, const float* __restrict__ Ws,
    const float* __restrict__ W1, const float* __restrict__ W2,
    unsigned short* __restrict__ wdf, unsigned short* __restrict__ wsf,
    unsigned short* __restrict__ w1f, unsigned short* __restrict__ w2f,
    float* __restrict__ zbuf) {
  int tid = blockIdx.x * 256 + threadIdx.x, n = gridDim.x * 256;
  pack_frags(Wd, 128, 0,    24, wdf,  98304,  tid, n);   // desc proj  [8mb][24ks]
  pack_frags(Ws, 128, 0,    4,  wsf,  16384,  tid, n);   // std proj   [8mb][4ks]
  pack_frags(W1, 512, 1152, 4,  w1f,  65536,  tid, n);   // W1[1152:]  [32mb][4ks]
  pack_frags(W2, 512, 0,    16, w2f,  262144, tid, n);   // W2         [32mb][16ks]
  for (int i = tid; i < 256; i += n) zbuf[i] = 0.f;      // zero page for masked rows
}

// ---------------- cc[b][h] = b1[h] + ctx(b).W1[:1152,h]  (fp32 exact) ----------------
__global__ __launch_bounds__(256) void ctx_cc(
    const float* __restrict__ instr, const float* __restrict__ state, const float* __restrict__ hidden,
    const float* __restrict__ W1, const float* __restrict__ b1, float* __restrict__ cc) {
  int bid = blockIdx.x;
  int b = bid >> 2, part = bid & 3;
  __shared__ float ctx[1152];
  __shared__ float red[256];
  int t = threadIdx.x;
  for (int i = t; i < 512; i += 256) { ctx[i] = instr[b * 512 + i]; ctx[512 + i] = state[b * 512 + i]; }
  if (t < 128) ctx[1024 + t] = hidden[b * 128 + t];
  __syncthreads();
  int hcol = part * 128 + (t & 127);
  int half = t >> 7;
  float acc = 0.f;
  const float* wp = W1 + (size_t)half * 576 * 512 + hcol;
  #pragma unroll 8
  for (int d = 0; d < 576; ++d) acc = fmaf(ctx[half * 576 + d], wp[(size_t)d * 512], acc);
  red[t] = acc;
  __syncthreads();
  if (t < 128) cc[b * 512 + hcol] = red[t] + red[t + 128] + b1[hcol];
}

// ---------------- q_inv[b]: MLP tail on emb=0 rows (f32 W2) ----------------
__global__ __launch_bounds__(256) void qinv_kernel(
    const float* __restrict__ cc, const float* __restrict__ W2, const float* __restrict__ b2,
    const float* __restrict__ W3, const float* __restrict__ b3, float* __restrict__ qinv) {
  int b = blockIdx.x, t = threadIdx.x;
  __shared__ float h1s[512];
  __shared__ float red[256];
  for (int i = t; i < 512; i += 256) h1s[i] = fmaxf(cc[b * 512 + i], 0.f);
  __syncthreads();
  float a0 = b2[t], a1 = b2[t + 256];
  #pragma unroll 4
  for (int c = 0; c < 512; ++c) {
    float x = h1s[c];
    a0 = fmaf(x, W2[(size_t)c * 512 + t], a0);
    a1 = fmaf(x, W2[(size_t)c * 512 + t + 256], a1);
  }
  red[t] = fmaxf(a0, 0.f) * W3[t] + fmaxf(a1, 0.f) * W3[t + 256];
  __syncthreads();
  for (int s = 128; s > 0; s >>= 1) { if (t < s) red[t] += red[t + s]; __syncthreads(); }
  if (t == 0) qinv[b] = fmaxf(red[0] + b3[0], 0.f);
}

// ---------------- E: emb producer. 32-row tiles, 256 threads, grid (16,128) ----------------
// DMA-staged f32 action chunks, 3-buffer ring, counted vmcnt, raw s_barrier.
// embB[(((tile*4+ks)*2+nb)*64 + lane)*8 + j] = bf16emb[r=nb*16+(lane&15)][k=ks*32+(lane>>4)*8+j]
__global__ __launch_bounds__(256, 3) void emb_kernel(
    const float* __restrict__ adesc, const float* __restrict__ astd,
    const int* __restrict__ type_ids, const int* __restrict__ lengths,
    const float* __restrict__ bdesc, const float* __restrict__ bstd,
    const unsigned short* __restrict__ wdf, const unsigned short* __restrict__ wsf,
    const float* __restrict__ zbuf,
    float* __restrict__ embout, unsigned short* __restrict__ embB) {
  int b = blockIdx.y, lt = blockIdx.x;
  int l0 = lt * 32;
  int t = threadIdx.x;
  int tile = b * 16 + lt;
  int len = lengths[b];
  int nv = len - l0; nv = nv < 0 ? 0 : (nv > 32 ? 32 : nv);
  f32x4 zero4 = {0.f, 0.f, 0.f, 0.f};

  if (nv == 0) {  // fully-invalid tile: emb = 0, embB = 0 (no barriers executed)
    float* ep = embout + (size_t)(b * 512 + l0) * 128;
    #pragma unroll
    for (int i = 0; i < 4; ++i) ((f32x4*)ep)[t + i * 256] = zero4;
    u32x4 z4 = {0u, 0u, 0u, 0u};
    u32x4* bp = (u32x4*)(embB + (size_t)tile * 4096);
    bp[t] = z4; bp[t + 256] = z4;
    return;
  }

  __shared__ __align__(16) char stage[3 * 16384];  // 3 x [32 rows][512B f32 chunk]
  __shared__ int typeL[32];
  int w = t >> 6, l = t & 63, g = l >> 4, ln = l & 15;

  if (t < 32) typeL[t] = type_ids[b * 512 + l0 + t];
  __syncthreads();

  // per-thread staging constants: 4 rows (i*8 + t>>5), 16B granule (t&31), src-side swizzle
  bool dval[4];
  const float* dP[4];
  const float* sP[4];
  const float* zP[4];
  #pragma unroll
  for (int i = 0; i < 4; ++i) {
    int r_i = i * 8 + (t >> 5);
    bool v = r_i < nv;
    int ty = v ? typeL[r_i] : -1;
    size_t gr = (size_t)(b * 512 + l0 + r_i);
    int swzf = ((((t & 31) * 16) ^ ((r_i & 7) << 4)) >> 2);  // float index, <128
    dval[i] = (ty == 0);
    dP[i] = adesc + gr * 768 + swzf;
    sP[i] = (v && ty != 0) ? (astd + gr * 128 + swzf) : (zbuf + swzf);
    zP[i] = zbuf + swzf;
  }

  auto issue = [&](int kc) {
    bool isStd = (kc == 6);
    char* dbase = stage + (kc % 3) * 16384 + w * 1024;
    #pragma unroll
    for (int i = 0; i < 4; ++i) {
      const float* src = isStd ? sP[i] : (dval[i] ? (dP[i] + kc * 128) : zP[i]);
      GLOAD_LDS16(src, dbase + i * 4096);
    }
  };

  f32x4 acc[2][2];
  #pragma unroll
  for (int mb = 0; mb < 2; ++mb)
    #pragma unroll
    for (int nb = 0; nb < 2; ++nb) acc[mb][nb] = zero4;

  auto mfma_chunk = [&](int kc) {
    const char* bp = stage + (kc % 3) * 16384;
    bool isStd = (kc == 6);
    #pragma unroll
    for (int ks = 0; ks < 4; ++ks) {
      short8_t bfr[2];
      #pragma unroll
      for (int nb = 0; nb < 2; ++nb) {
        int row = nb * 16 + ln;
        int s = (row & 7) << 4;
        int kb = ks * 128 + g * 32;
        f32x4 lo = *(const f32x4*)(bp + row * 512 + (kb ^ s));
        f32x4 hi = *(const f32x4*)(bp + row * 512 + ((kb + 16) ^ s));
        short8_t bb;
        bb[0] = (short)cvt1(lo[0]); bb[1] = (short)cvt1(lo[1]);
        bb[2] = (short)cvt1(lo[2]); bb[3] = (short)cvt1(lo[3]);
        bb[4] = (short)cvt1(hi[0]); bb[5] = (short)cvt1(hi[1]);
        bb[6] = (short)cvt1(hi[2]); bb[7] = (short)cvt1(hi[3]);
        bfr[nb] = bb;
      }
      #pragma unroll
      for (int mb = 0; mb < 2; ++mb) {
        const unsigned short* ap = isStd ? (wsf + ((((w * 2 + mb) * 4 + ks) * 64 + l) << 3))
                                         : (wdf + ((((w * 2 + mb) * 24 + kc * 4 + ks) * 64 + l) << 3));
        short8_t a = *(const short8_t*)ap;
        acc[mb][0] = __builtin_amdgcn_mfma_f32_16x16x32_bf16(a, bfr[0], acc[mb][0], 0, 0, 0);
        acc[mb][1] = __builtin_amdgcn_mfma_f32_16x16x32_bf16(a, bfr[1], acc[mb][1], 0, 0, 0);
      }
    }
  };

  // prologue: 2 chunks in flight (8 DMA ops outstanding per wave)
  issue(0);
  issue(1);

  #pragma unroll
  for (int kc = 0; kc < 7; ++kc) {
    __builtin_amdgcn_sched_barrier(0);
    if (kc < 6) { asm volatile("s_waitcnt vmcnt(4)" ::: "memory"); }
    else        { asm volatile("s_waitcnt vmcnt(0)" ::: "memory"); }
    __builtin_amdgcn_s_barrier();            // all waves' chunk-kc DMA complete
    __builtin_amdgcn_sched_barrier(0);
    if (kc + 2 <= 6) issue(kc + 2);          // buf (kc+2)%3 == (kc-1)%3: freed by this barrier
    mfma_chunk(kc);
  }

  // epilogue: masked bias + f32 global store + bf16 -> E (buf[1] region; chunks 5,6 used bufs 2,0)
  unsigned short* E = (unsigned short*)(stage + 16384);
  #pragma unroll
  for (int mb = 0; mb < 2; ++mb) {
    int k0 = w * 32 + mb * 16 + g * 4;
    f32x4 bd4 = *(const f32x4*)(bdesc + k0);
    f32x4 bs4 = *(const f32x4*)(bstd + k0);
    #pragma unroll
    for (int nb = 0; nb < 2; ++nb) {
      int r = nb * 16 + ln;
      f32x4 e = acc[mb][nb];
      if (r < nv) { f32x4 bias = (typeL[r] == 0) ? bd4 : bs4; e = e + bias; }
      else e = zero4;
      *(f32x4*)(embout + (size_t)(b * 512 + l0 + r) * 128 + k0) = e;
      short4_t p; p[0] = (short)f2bf(e[0]); p[1] = (short)f2bf(e[1]);
      p[2] = (short)f2bf(e[2]); p[3] = (short)f2bf(e[3]);
      *(short4_t*)&E[r * 136 + k0] = p;
    }
  }
  __syncthreads();

  // export B-frag-linear embB (coalesced 1KB stores)
  unsigned short* bbase = embB + (size_t)tile * 4096;
  #pragma unroll
  for (int ks = 0; ks < 4; ++ks)
    #pragma unroll
    for (int nb = 0; nb < 2; ++nb) {
      short8_t v = *(const short8_t*)&E[(nb * 16 + ln) * 136 + ks * 32 + g * 8];
      *(short8_t*)&bbase[((ks * 2 + nb) * 64 + l) * 8] = v;
    }
}

// ---------------- M: MLP. 128-row blocks, 512 thr, grid (4,128) ---- (v8, unchanged) ----
__global__ __launch_bounds__(512, 2) void mlp_kernel(
    const int* __restrict__ lengths,
    const float* __restrict__ b2, const float* __restrict__ W3, const float* __restrict__ b3,
    const unsigned short* __restrict__ w1f, const unsigned short* __restrict__ w2f,
    const float* __restrict__ cc, const float* __restrict__ qinv,
    const unsigned short* __restrict__ embB, float* __restrict__ qout) {
  int b = blockIdx.y, lt = blockIdx.x;
  int l0 = lt * 128;
  int t = threadIdx.x;
  int len = lengths[b];
  int nv = len - l0; nv = nv < 0 ? 0 : (nv > 128 ? 128 : nv);

  if (nv == 0) {
    if (t < 128) qout[(size_t)b * 512 + l0 + t] = qinv[b];
    return;
  }

  __shared__ __align__(16) unsigned short h1[128 * 512];  // XOR-swizzled
  __shared__ float qpart[8][128];
  int w = t >> 6, l = t & 63, g = l >> 4, ln = l & 15;

  // ===== S1
  f32x4 acc[4][8];
  #pragma unroll
  for (int mbi = 0; mbi < 4; ++mbi) {
    f32x4 ccv = *(const f32x4*)(cc + (size_t)b * 512 + (w * 4 + mbi) * 16 + g * 4);
    #pragma unroll
    for (int nb = 0; nb < 8; ++nb) acc[mbi][nb] = ccv;
  }
  const unsigned short* ebase = embB + (size_t)(b * 16 + lt * 4) * 4096;
  #pragma unroll
  for (int kk = 0; kk < 4; ++kk) {
    int ks = (kk + w) & 3;
    short8_t bfr[8];
    #pragma unroll
    for (int nb = 0; nb < 8; ++nb)
      bfr[nb] = *(const short8_t*)&ebase[(nb >> 1) * 4096 + ((ks * 2 + (nb & 1)) * 64 + l) * 8];
    short8_t a[4];
    #pragma unroll
    for (int mbi = 0; mbi < 4; ++mbi)
      a[mbi] = *(const short8_t*)(w1f + ((((w * 4 + mbi) * 4 + ks) * 64 + l) << 3));
    __builtin_amdgcn_s_setprio(1);
    #pragma unroll
    for (int mbi = 0; mbi < 4; ++mbi)
      #pragma unroll
      for (int nb = 0; nb < 8; ++nb)
        acc[mbi][nb] = __builtin_amdgcn_mfma_f32_16x16x32_bf16(a[mbi], bfr[nb], acc[mbi][nb], 0, 0, 0);
    __builtin_amdgcn_s_setprio(0);
  }
  #pragma unroll
  for (int mbi = 0; mbi < 4; ++mbi) {
    int c0 = (w * 4 + mbi) * 16 + g * 4;
    #pragma unroll
    for (int nb = 0; nb < 8; ++nb) {
      int r = nb * 16 + ln;
      f32x4 v = acc[mbi][nb];
      short4_t p;
      p[0] = (short)f2bf(fmaxf(v[0], 0.f)); p[1] = (short)f2bf(fmaxf(v[1], 0.f));
      p[2] = (short)f2bf(fmaxf(v[2], 0.f)); p[3] = (short)f2bf(fmaxf(v[3], 0.f));
      *(short4_t*)&h1[r * 512 + (c0 ^ ((r & 7) << 3))] = p;
    }
  }
  __syncthreads();

  // ===== S2
  #pragma unroll
  for (int mbi = 0; mbi < 4; ++mbi) {
    f32x4 b2v = *(const f32x4*)(b2 + (w * 4 + mbi) * 16 + g * 4);
    #pragma unroll
    for (int nb = 0; nb < 8; ++nb) acc[mbi][nb] = b2v;
  }
  int ks0 = (2 * w) & 15;
  short8_t aP[2][4];
  #pragma unroll
  for (int mbi = 0; mbi < 4; ++mbi)
    aP[0][mbi] = *(const short8_t*)(w2f + ((((w * 4 + mbi) * 16 + ks0) * 64 + l) << 3));
  #pragma unroll
  for (int kk = 0; kk < 16; ++kk) {
    int ksn = (kk + 1 + 2 * w) & 15;
    if (kk < 15) {
      #pragma unroll
      for (int mbi = 0; mbi < 4; ++mbi)
        aP[(kk + 1) & 1][mbi] =
            *(const short8_t*)(w2f + ((((w * 4 + mbi) * 16 + ksn) * 64 + l) << 3));
    }
    int ks = (kk + 2 * w) & 15;
    short8_t bfr[8];
    #pragma unroll
    for (int nb = 0; nb < 8; ++nb) {
      int row = nb * 16 + ln;
      bfr[nb] = *(const short8_t*)&h1[row * 512 + ((ks * 32 + g * 8) ^ ((row & 7) << 3))];
    }
    __builtin_amdgcn_s_setprio(1);
    #pragma unroll
    for (int mbi = 0; mbi < 4; ++mbi)
      #pragma unroll
      for (int nb = 0; nb < 8; ++nb)
        acc[mbi][nb] = __builtin_amdgcn_mfma_f32_16x16x32_bf16(aP[kk & 1][mbi], bfr[nb], acc[mbi][nb], 0, 0, 0);
    __builtin_amdgcn_s_setprio(0);
  }

  // ===== S3
  float part[8] = {0.f, 0.f, 0.f, 0.f, 0.f, 0.f, 0.f, 0.f};
  #pragma unroll
  for (int mbi = 0; mbi < 4; ++mbi) {
    int c0 = (w * 4 + mbi) * 16 + g * 4;
    f32x4 w3v = *(const f32x4*)(W3 + c0);
    #pragma unroll
    for (int nb = 0; nb < 8; ++nb) {
      f32x4 v = acc[mbi][nb];
      part[nb] += fmaxf(v[0], 0.f) * w3v[0] + fmaxf(v[1], 0.f) * w3v[1]
                + fmaxf(v[2], 0.f) * w3v[2] + fmaxf(v[3], 0.f) * w3v[3];
    }
  }
  #pragma unroll
  for (int nb = 0; nb < 8; ++nb) {
    float p = part[nb];
    p += __shfl_xor(p, 16, 64);
    p += __shfl_xor(p, 32, 64);
    if (g == 0) qpart[w][nb * 16 + ln] = p;
  }
  __syncthreads();
  if (t < 128) {
    float q = qpart[0][t] + qpart[1][t] + qpart[2][t] + qpart[3][t]
            + qpart[4][t] + qpart[5][t] + qpart[6][t] + qpart[7][t] + b3[0];
    qout[(size_t)b * 512 + l0 + t] = fmaxf(q, 0.f);
  }
}

extern "C" void kernel_launch(void* const* d_in, const int* in_sizes, int n_in,
                              void* d_out, int out_size, void* d_ws, size_t ws_size,
                              hipStream_t stream) {
  (void)in_sizes; (void)n_in; (void)out_size; (void)ws_size;
  const float* instr  = (const float*)d_in[0];
  const float* state  = (const float*)d_in[1];
  const float* hidden = (const float*)d_in[2];
  const float* adesc  = (const float*)d_in[3];
  const float* astd   = (const float*)d_in[4];
  const int*   tids   = (const int*)d_in[5];
  const int*   lens   = (const int*)d_in[6];
  const float* Wd = (const float*)d_in[7];
  const float* bd = (const float*)d_in[8];
  const float* Ws = (const float*)d_in[9];
  const float* bs = (const float*)d_in[10];
  const float* W1 = (const float*)d_in[11];
  const float* b1 = (const float*)d_in[12];
  const float* W2 = (const float*)d_in[13];
  const float* b2 = (const float*)d_in[14];
  const float* W3 = (const float*)d_in[15];
  const float* b3 = (const float*)d_in[16];

  float* qout = (float*)d_out;
  float* embout = qout + 128 * 512;

  char* ws = (char*)d_ws;
  unsigned short* wdf  = (unsigned short*)(ws);             // 196608 B
  unsigned short* wsf  = (unsigned short*)(ws + 196608);    //  32768 B
  unsigned short* w1f  = (unsigned short*)(ws + 229376);    // 131072 B
  unsigned short* w2f  = (unsigned short*)(ws + 360448);    // 524288 B
  float* cc   = (float*)(ws + 884736);                      // 262144 B
  float* qinv = (float*)(ws + 1146880);                     // 512 B
  unsigned short* embB = (unsigned short*)(ws + 1147392);   // 16777216 B
  float* zbuf = (float*)(ws + 17924608);                    // 1024 B zeros

  prep_pack<<<256, 256, 0, stream>>>(Wd, Ws, W1, W2, wdf, wsf, w1f, w2f, zbuf);
  ctx_cc<<<512, 256, 0, stream>>>(instr, state, hidden, W1, b1, cc);
  qinv_kernel<<<128, 256, 0, stream>>>(cc, W2, b2, W3, b3, qinv);
  emb_kernel<<<dim3(16, 128), 256, 0, stream>>>(adesc, astd, tids, lens, bd, bs,
                                                wdf, wsf, zbuf, embout, embB);
  mlp_kernel<<<dim3(4, 128), 512, 0, stream>>>(lens, b2, W3, b3, w1f, w2f,
                                               cc, qinv, embB, qout);
}